// Round 1
// 1926.995 us; speedup vs baseline: 1.9338x; 1.9338x over previous
//
#include <hip/hip_runtime.h>
#include <hip/hip_bf16.h>

// ---------------- problem constants ----------------
#define BSZ 64
#define SEQ 2048
#define HD  256
#define ND  256
#define BS_TOK (BSZ*SEQ)          // 131072 tokens
#define NCAND 101
#define EPS 1e-5f

using bf16 = __hip_bfloat16;
typedef unsigned short u16;
typedef unsigned int   u32;
typedef __attribute__((ext_vector_type(8))) short short8v;   // 8 bf16 (4 VGPRs)
typedef __attribute__((ext_vector_type(4))) float f32x4;

__device__ __forceinline__ float clampf(float v, float c) { return fminf(fmaxf(v, -c), c); }

// fp32 -> (hi,lo) bf16 split: x ~= hi + lo, |x-(hi+lo)| <~ 2^-17 |x|
__device__ __forceinline__ void split_bf(float x, u16& h, u16& l) {
  u32 u = __float_as_uint(x);
  h = (u16)(u >> 16);
  float d = x - __uint_as_float(u & 0xffff0000u);
  l = (u16)(__float_as_uint(d) >> 16);
}

// ---------------- workspace layout ----------------
// [0,128Mi)     : Xf fp32 [BS_TOK,256]
// [128Mi,132Mi) : pr fp32[1024]; bf16 hi/lo weight planes (2 MiB); finals
// [132Mi,...)   : chunks: Hb fp32 [CB*SEQ,256], Sb fp32 [CB*SEQ,512]
static constexpr size_t MiB = 1024*1024;
static constexpr size_t OFF_X    = 0;
static constexpr size_t OFF_PR   = 128*MiB;                   // fp32[1024]: abr[512] abi[512]
static constexpr size_t OFF_WB   = OFF_PR + 4096;             // u16[1048576] = 2 MiB, layout below
static constexpr size_t OFF_XLR  = OFF_WB + 2*MiB;            // fp32[64*256]
static constexpr size_t OFF_XLI  = OFF_XLR + 65536;
static constexpr size_t OFF_YL   = OFF_XLI + 65536;
static constexpr size_t OFF_XF   = OFF_YL  + 65536;
static constexpr size_t OFF_CH   = 132*MiB;

// wb (u16 element offsets):
//  Bb0h 0        Bb0l 131072   Bb1h 262144   Bb1l 393216   (each [512 cols][K=256])
//  Wsh  524288   Wsl  655360                               ([256 cols][K=512])
//  W1h  786432   W1l  851968   W2h 917504    W2l 983040    ([256 cols][K=256])
static constexpr int WB_BB0H = 0,      WB_BB0L = 131072;
static constexpr int WB_BB1H = 262144, WB_BB1L = 393216;
static constexpr int WB_WSH  = 524288, WB_WSL  = 655360;
static constexpr int WB_W1H  = 786432, WB_W1L  = 851968;
static constexpr int WB_W2H  = 917504, WB_W2L  = 983040;

// ---------------- param pack (weights pre-split to bf16 hi/lo, k-major) ----------------
__global__ __launch_bounds__(256) void pack_k(
    const float* __restrict__ lar, const float* __restrict__ aim, const float* __restrict__ lstep,
    const float* __restrict__ C0, const float* __restrict__ W1, const float* __restrict__ W2,
    const float* __restrict__ Bf,
    float* __restrict__ pr, u16* __restrict__ wb)
{
  int gid = blockIdx.x*256 + threadIdx.x;   // grid 256 -> 65536
  if (gid < 512) {
    int blk = gid >> 8;
    float step = expf(clampf(lstep[blk], 10.f));
    float ar = -expf(clampf(lar[gid], 20.f));
    float ai = aim[gid];
    float er = expf(fminf(ar*step, 0.f));
    pr[gid]       = er * cosf(ai*step);
    pr[512 + gid] = er * sinf(ai*step);
  }
  int r = gid >> 8, c = gid & 255;          // r = n (state) / output col, c = h (hidden) / k
  u16 h, l;
#pragma unroll
  for (int blk = 0; blk < 2; ++blk) {
    float step = expf(clampf(lstep[blk], 10.f));
    float ar = -expf(clampf(lar[blk*256 + c], 20.f));
    float ai = aim[blk*256 + c];
    float er  = expf(fminf(ar*step, 0.f));
    float abr = er * cosf(ai*step);
    float abi = er * sinf(ai*step);
    float den = ar*ar + ai*ai;
    float tr = abr - 1.f, ti = abi;
    float cr = (tr*ar + ti*ai) / den;
    float ci = (ti*ar - tr*ai) / den;
    float bv = Bf[blk*65536 + r*256 + c];
    u16* Bbh = wb + (blk ? WB_BB1H : WB_BB0H);
    u16* Bbl = wb + (blk ? WB_BB1L : WB_BB0L);
    split_bf(cr * bv, h, l); Bbh[r*256 + c] = h;        Bbl[r*256 + c] = l;
    split_bf(ci * bv, h, l); Bbh[(256+r)*256 + c] = h;  Bbl[(256+r)*256 + c] = l;
  }
  // Wstk: col = h (r), k = stacked n (c | 256+c), K=512
  split_bf( C0[(size_t)(r*256 + c)*2    ], h, l); wb[WB_WSH + r*512 + c] = h;       wb[WB_WSL + r*512 + c] = l;
  split_bf(-C0[(size_t)(r*256 + c)*2 + 1], h, l); wb[WB_WSH + r*512 + 256 + c] = h; wb[WB_WSL + r*512 + 256 + c] = l;
  // W1T/W2T: col = n (r), k = c
  split_bf(W1[c*256 + r], h, l); wb[WB_W1H + r*256 + c] = h; wb[WB_W1L + r*256 + c] = l;
  split_bf(W2[c*256 + r], h, l); wb[WB_W2H + r*256 + c] = h; wb[WB_W2L + r*256 + c] = l;
}

// ---------------- embedding + mask ----------------
__global__ __launch_bounds__(256) void embed_k(
    const int* __restrict__ seqs, const float* __restrict__ iemb,
    const float* __restrict__ pemb, float* __restrict__ Xf)
{
  int token = blockIdx.x; int h = threadIdx.x;
  int id = seqs[token];
  int pos = token & (SEQ-1);
  float v = 0.f;
  if (id != 0) v = iemb[(size_t)id*HD + h] + pemb[(size_t)pos*HD + h];
  Xf[(size_t)token*HD + h] = v;
}

// ---------------- LayerNorm (1 wave per row); ADD_DU folds Xf += D*u ----------------
template<bool ADD_DU>
__global__ __launch_bounds__(256) void ln_rows(
    float* __restrict__ Xf, const float* __restrict__ g, const float* __restrict__ b,
    float* __restrict__ out, const float* __restrict__ Dv)
{
  int w = threadIdx.x >> 6, lane = threadIdx.x & 63;
  size_t row = (size_t)blockIdx.x * 4 + w;
  float* xrow = Xf + row*HD;
  float4 xv = ((const float4*)xrow)[lane];
  float x[4] = {xv.x, xv.y, xv.z, xv.w};
  float s = 0.f, s2 = 0.f;
#pragma unroll
  for (int k = 0; k < 4; ++k) { s += x[k]; s2 += x[k]*x[k]; }
#pragma unroll
  for (int off = 32; off > 0; off >>= 1) { s += __shfl_xor(s, off, 64); s2 += __shfl_xor(s2, off, 64); }
  float m = s * (1.f/256.f);
  float var = fmaxf(s2 * (1.f/256.f) - m*m, 0.f);
  float rinv = rsqrtf(var + EPS);
  int c0 = lane*4;
  float u[4], nx[4];
#pragma unroll
  for (int k = 0; k < 4; ++k) {
    u[k] = (x[k] - m) * rinv * g[c0+k] + b[c0+k];
    if (ADD_DU) nx[k] = x[k] + Dv[c0+k] * u[k];
  }
  ((float4*)(out + row*HD))[lane] = make_float4(u[0], u[1], u[2], u[3]);
  if (ADD_DU) ((float4*)xrow)[lane] = make_float4(nx[0], nx[1], nx[2], nx[3]);
}

// ---------------- split-bf16 MFMA GEMM ----------------
// out[m,n] = sum_k A[m,k] * W[n,k], A fp32 (converted to hi/lo bf16 on the fly),
// W pre-split bf16 hi/lo planes (k-major). 128x128 tile, 4 waves 2x2, each 64x64.
// Products kept: Ah*Bh + Ah*Bl + Al*Bh  (Al*Bl term ~2^-16 rel, dropped).
// EPI: 0 = O[row*ldo+col] = v
//      2 = O = relu(v + bias[col])
//      3 = Xf = (Xf + v + bias[col]) * mask(ids[row])
//      4 = Xf += v
template<int EPI>
__global__ __launch_bounds__(256) void mgemm(
    const float* __restrict__ A, int lda,
    const u16* __restrict__ Bh, const u16* __restrict__ Bl, int K, int ldo,
    float* __restrict__ Xf, float* __restrict__ O,
    const float* __restrict__ bias, const int* __restrict__ ids)
{
  // A tile in LDS as hi/lo bf16, rows of 64 k (128 B) with 16B-unit XOR swizzle
  __shared__ __align__(16) u16 Ah[128*64];
  __shared__ __align__(16) u16 Al[128*64];
  const int tid  = threadIdx.x;
  const int lane = tid & 63, wid = tid >> 6;
  const int wr = wid >> 1, wc = wid & 1;          // 2x2 wave grid
  const int l16 = lane & 15, lhi = lane >> 4;
  const int m0 = blockIdx.y * 128;
  const int n0 = blockIdx.x * 128 + wc*64;        // wave's col base
  f32x4 acc[4][4] = {};                           // [row-frag][col-frag]

  for (int kb = 0; kb < K; kb += 64) {
    __syncthreads();
    // stage A: 128 rows x 64 k -> hi/lo bf16 (swizzled). 1024 16B-chunks, 4/thread.
#pragma unroll
    for (int j = 0; j < 4; ++j) {
      int chunk = tid + 256*j;                    // 0..1023
      int r = chunk >> 3, c8 = chunk & 7;
      const float* ap = A + (size_t)(m0 + r)*lda + kb + c8*8;
      float4 v0 = ((const float4*)ap)[0];
      float4 v1 = ((const float4*)ap)[1];
      float vv[8] = {v0.x, v0.y, v0.z, v0.w, v1.x, v1.y, v1.z, v1.w};
      short8v hv, lv;
#pragma unroll
      for (int e = 0; e < 8; ++e) {
        u16 h, l; split_bf(vv[e], h, l);
        hv[e] = (short)h; lv[e] = (short)l;
      }
      int off = r*64 + ((c8 ^ (r & 7)) << 3);
      *(short8v*)&Ah[off] = hv;
      *(short8v*)&Al[off] = lv;
    }
    __syncthreads();
#pragma unroll
    for (int kk = 0; kk < 64; kk += 32) {
      // A frags: row = wave_row + rf*16 + l16, k = kk + lhi*8 + [0..7]
      short8v ahf[4], alf[4];
      const int c8r = (kk >> 3) + lhi;
#pragma unroll
      for (int rf = 0; rf < 4; ++rf) {
        int r = wr*64 + rf*16 + l16;
        int off = r*64 + ((c8r ^ (r & 7)) << 3);
        ahf[rf] = *(const short8v*)&Ah[off];
        alf[rf] = *(const short8v*)&Al[off];
      }
#pragma unroll
      for (int nf = 0; nf < 4; ++nf) {
        // B frags straight from global (L2-resident): col = n0+nf*16+l16, k contiguous
        size_t bo = (size_t)(n0 + nf*16 + l16)*K + kb + kk + lhi*8;
        short8v bh = *(const short8v*)(Bh + bo);
        short8v bl = *(const short8v*)(Bl + bo);
#pragma unroll
        for (int rf = 0; rf < 4; ++rf) {
          f32x4 c = acc[rf][nf];
          c = __builtin_amdgcn_mfma_f32_16x16x32_bf16(alf[rf], bh, c, 0, 0, 0);
          c = __builtin_amdgcn_mfma_f32_16x16x32_bf16(ahf[rf], bl, c, 0, 0, 0);
          c = __builtin_amdgcn_mfma_f32_16x16x32_bf16(ahf[rf], bh, c, 0, 0, 0);
          acc[rf][nf] = c;
        }
      }
    }
  }
  // epilogue: D frag lane map: col = l16, row = lhi*4 + j  (per 16x16 fragment)
#pragma unroll
  for (int rf = 0; rf < 4; ++rf) {
#pragma unroll
    for (int j = 0; j < 4; ++j) {
      int row = m0 + wr*64 + rf*16 + lhi*4 + j;
      int idv = 0;
      if (EPI == 3) idv = ids[row];
#pragma unroll
      for (int nf = 0; nf < 4; ++nf) {
        int col = n0 + nf*16 + l16;
        size_t idx = (size_t)row*ldo + col;
        float v = acc[rf][nf][j];
        if (EPI == 0) {
          O[idx] = v;
        } else if (EPI == 2) {
          O[idx] = fmaxf(v + bias[col], 0.f);
        } else if (EPI == 3) {
          float t = Xf[idx] + v + bias[col];
          Xf[idx] = (idv != 0) ? t : 0.f;
        } else {
          Xf[idx] = Xf[idx] + v;
        }
      }
    }
  }
}

// ---------------- diagonal complex scan; Sb [rows,512] = [v_r|v_i] in place ----------------
template<bool STORE>
__global__ __launch_bounds__(64) void scan_k(
    float* __restrict__ Sb,
    const float* __restrict__ arp, const float* __restrict__ aip,
    float* __restrict__ xlast_r, float* __restrict__ xlast_i)
{
  int lane = threadIdx.x;
  int b = blockIdx.x >> 2;                    // chunk-local batch
  int n = ((blockIdx.x & 3) << 6) | lane;
  float Ar = arp[n], Ai = aip[n];
  float xr = 0.f, xi = 0.f;
  float* sp = Sb + (size_t)b*SEQ*512 + n;
  for (int t = 0; t < SEQ; ++t) {
    float sr = sp[0], si = sp[256];
    float nxr = Ar*xr - Ai*xi + sr;
    float nxi = Ar*xi + Ai*xr + si;
    xr = nxr; xi = nxi;
    if (STORE) { sp[0] = xr; sp[256] = xi; }
    sp += 512;
  }
  if (!STORE) { xlast_r[b*ND + n] = xr; xlast_i[b*ND + n] = xi; }
}

// ---------------- block-1 last-position tail ----------------
__global__ __launch_bounds__(256) void ylast_k(
    const float* __restrict__ xr, const float* __restrict__ xi,   // pre-offset (chunk)
    const float* __restrict__ C1, const float* __restrict__ D1,
    const float* __restrict__ U,                                  // chunk-local Hb (block-1 u)
    const float* __restrict__ Xf, int b0, float* __restrict__ ylr)
{
  int bl = blockIdx.x, h = threadIdx.x;
  __shared__ float sxr[256], sxi[256];
  sxr[h] = xr[bl*256 + h]; sxi[h] = xi[bl*256 + h];
  __syncthreads();
  float acc = 0.f;
  for (int n = 0; n < 256; ++n) {
    acc += C1[(size_t)(h*256 + n)*2] * sxr[n] - C1[(size_t)(h*256 + n)*2 + 1] * sxi[n];
  }
  size_t lidx = ((size_t)bl*SEQ + SEQ - 1)*HD + h;
  size_t gidx = ((size_t)(b0 + bl)*SEQ + SEQ - 1)*HD + h;
  ylr[(b0 + bl)*256 + h] = Xf[gidx] + acc + D1[h] * U[lidx];
}

__device__ __forceinline__ float block_sum256(float v, volatile float* red) {
#pragma unroll
  for (int off = 32; off > 0; off >>= 1) v += __shfl_xor(v, off, 64);
  int w = threadIdx.x >> 6;
  __syncthreads();
  if ((threadIdx.x & 63) == 0) red[w] = v;
  __syncthreads();
  return red[0] + red[1] + red[2] + red[3];
}

__global__ __launch_bounds__(256) void tail_k(
    const float* __restrict__ ylr, const float* __restrict__ g1, const float* __restrict__ bb1,
    const float* __restrict__ W1p, const float* __restrict__ b1p,
    const float* __restrict__ W2p, const float* __restrict__ b2p,
    const float* __restrict__ fg, const float* __restrict__ fb,
    const int* __restrict__ seqs, float* __restrict__ xfin)
{
  __shared__ float sh[256];
  __shared__ float red[4];
  int b = blockIdx.x, h = threadIdx.x;
  float x = ylr[b*256 + h];
  float m = block_sum256(x, red) * (1.f/256.f);
  float d = x - m;
  float var = fmaxf(block_sum256(d*d, red) * (1.f/256.f), 0.f);
  float h2 = d * rsqrtf(var + EPS) * g1[h] + bb1[h];
  __syncthreads();
  sh[h] = h2;
  __syncthreads();
  float acc = 0.f;
  for (int k = 0; k < 256; ++k) acc += sh[k] * W1p[k*256 + h];
  float f = fmaxf(acc + b1p[h], 0.f);
  __syncthreads();
  sh[h] = f;
  __syncthreads();
  acc = 0.f;
  for (int k = 0; k < 256; ++k) acc += sh[k] * W2p[k*256 + h];
  float x2 = x + acc + b2p[h];
  if (seqs[b*SEQ + SEQ - 1] == 0) x2 = 0.f;
  float m2 = block_sum256(x2, red) * (1.f/256.f);
  float d2 = x2 - m2;
  float v2 = fmaxf(block_sum256(d2*d2, red) * (1.f/256.f), 0.f);
  xfin[b*256 + h] = d2 * rsqrtf(v2 + EPS) * fg[h] + fb[h];
}

// NOTE: reference output dtype is float32 -> d_out is float*.
__global__ __launch_bounds__(256) void logits_k(
    const float* __restrict__ xfin, const int* __restrict__ cand,
    const float* __restrict__ iemb, float* __restrict__ out)
{
  int gid = blockIdx.x*4 + (threadIdx.x >> 6);
  if (gid >= BSZ*NCAND) return;
  int lane = threadIdx.x & 63;
  int b = gid / NCAND;
  int id = cand[gid];
  const float* e  = iemb + (size_t)id*HD;
  const float* xv = xfin + b*256;
  float acc = 0.f;
#pragma unroll
  for (int k = 0; k < 4; ++k) acc += xv[lane*4 + k] * e[lane*4 + k];
#pragma unroll
  for (int off = 32; off > 0; off >>= 1) acc += __shfl_xor(acc, off, 64);
  if (lane == 0) out[gid] = acc;
}

// ---------------- launch ----------------
extern "C" void kernel_launch(void* const* d_in, const int* in_sizes, int n_in,
                              void* d_out, int out_size, void* d_ws, size_t ws_size,
                              hipStream_t stream)
{
  const int*   seqs  = (const int*)d_in[0];
  const int*   cand  = (const int*)d_in[1];
  const float* iemb  = (const float*)d_in[2];
  const float* pemb  = (const float*)d_in[3];
  const float* ln_g  = (const float*)d_in[4];
  const float* ln_b  = (const float*)d_in[5];
  const float* lar   = (const float*)d_in[6];
  const float* aim   = (const float*)d_in[7];
  const float* Bssm  = (const float*)d_in[8];
  const float* Cssm  = (const float*)d_in[9];
  const float* Dssm  = (const float*)d_in[10];
  const float* lstep = (const float*)d_in[11];
  const float* W1    = (const float*)d_in[12];
  const float* b1    = (const float*)d_in[13];
  const float* W2    = (const float*)d_in[14];
  const float* b2    = (const float*)d_in[15];
  const float* lnfg  = (const float*)d_in[16];
  const float* lnfb  = (const float*)d_in[17];

  char* ws = (char*)d_ws;
  float* Xf   = (float*)(ws + OFF_X);
  float* pr   = (float*)(ws + OFF_PR);
  u16*   wb   = (u16*)  (ws + OFF_WB);
  float* xlr  = (float*)(ws + OFF_XLR);
  float* xli  = (float*)(ws + OFF_XLI);
  float* ylr  = (float*)(ws + OFF_YL);
  float* xfin = (float*)(ws + OFF_XF);

  // adaptive chunk size: Hb = 2*CB MiB, Sb = 4*CB MiB
  int CB = 64;
  while (CB > 1 && (OFF_CH + (size_t)6*CB*MiB) > ws_size) CB >>= 1;
  float* HbC = (float*)(ws + OFF_CH);
  float* SbC = (float*)(ws + OFF_CH + (size_t)2*CB*MiB);

  pack_k<<<256, 256, 0, stream>>>(lar, aim, lstep, Cssm, W1, W2, Bssm, pr, wb);
  embed_k<<<BS_TOK, 256, 0, stream>>>(seqs, iemb, pemb, Xf);

  const int rows = CB*SEQ;
  const int rb   = rows / 128;
  for (int b0 = 0; b0 < BSZ; b0 += CB) {
    float* XfC = Xf + (size_t)b0*SEQ*HD;
    const int* seqC = seqs + (size_t)b0*SEQ;

    // ---- block 0: S4 ----
    ln_rows<true><<<rows/4, 256, 0, stream>>>(XfC, ln_g, ln_b, HbC, Dssm);
    mgemm<0><<<dim3(4, rb), 256, 0, stream>>>(HbC, 256, wb + WB_BB0H, wb + WB_BB0L, 256, 512,
                                              nullptr, SbC, nullptr, nullptr);
    scan_k<true><<<CB*4, 64, 0, stream>>>(SbC, pr, pr+512, nullptr, nullptr);
    mgemm<4><<<dim3(2, rb), 256, 0, stream>>>(SbC, 512, wb + WB_WSH, wb + WB_WSL, 512, 256,
                                              XfC, nullptr, nullptr, nullptr);
    // ---- block 0: FFN ----
    ln_rows<false><<<rows/4, 256, 0, stream>>>(XfC, ln_g, ln_b, HbC, nullptr);
    mgemm<2><<<dim3(2, rb), 256, 0, stream>>>(HbC, 256, wb + WB_W1H, wb + WB_W1L, 256, 256,
                                              nullptr, SbC, b1, nullptr);
    mgemm<3><<<dim3(2, rb), 256, 0, stream>>>(SbC, 256, wb + WB_W2H, wb + WB_W2L, 256, 256,
                                              XfC, nullptr, b2, seqC);
    // ---- block 1 (only last position needed downstream of the scan) ----
    ln_rows<false><<<rows/4, 256, 0, stream>>>(XfC, ln_g + 256, ln_b + 256, HbC, nullptr);
    mgemm<0><<<dim3(4, rb), 256, 0, stream>>>(HbC, 256, wb + WB_BB1H, wb + WB_BB1L, 256, 512,
                                              nullptr, SbC, nullptr, nullptr);
    scan_k<false><<<CB*4, 64, 0, stream>>>(SbC, pr+256, pr+768, xlr + b0*256, xli + b0*256);
    ylast_k<<<CB, 256, 0, stream>>>(xlr + b0*256, xli + b0*256, Cssm + 2*65536, Dssm + 256,
                                    HbC, Xf, b0, ylr);
  }

  tail_k<<<BSZ, 256, 0, stream>>>(ylr, ln_g + 256, ln_b + 256, W1 + 65536, b1 + 256,
                                  W2 + 65536, b2 + 256, lnfg, lnfb, seqs, xfin);
  logits_k<<<(BSZ*NCAND + 3)/4, 256, 0, stream>>>(xfin, cand, iemb, (float*)d_out);
}